// Round 1
// baseline (17616.180 us; speedup 1.0000x reference)
//
#include <hip/hip_runtime.h>

// ---------------------------------------------------------------------------
// Decagon GCN forward: 5 layers of heterogeneous GraphConvolutionMulti.
// Layer: for edge type t=(i,j): out_i += adj_t @ (act(h_j) @ W[t])
// Edge types: (0,0),(0,1),(1,0),(1,1).
// Round 1: correctness-first fp32. GEMM = LDS-tiled VALU fp32 (no fp32 MFMA
// on CDNA4). Scatter = atomicAdd f32 (expected bottleneck; CSR next round).
// ---------------------------------------------------------------------------

#define HDIM 64

// C[N,64] = act(A)[N,K] @ W[K,64], K in {64,128}, act = relu if RELU.
// Block: 256 threads = 16x16, each thread computes a 4x4 micro-tile of a
// 64(rows) x 64(cols) block tile. W staged fully in LDS; A staged k-major
// in 16-wide K chunks with +4 padding (stride 68) for bank spread.
template <int RELU>
__global__ __launch_bounds__(256) void gemm64(const float* __restrict__ A,
                                              const float* __restrict__ W,
                                              float* __restrict__ C,
                                              int N, int K) {
    __shared__ __align__(16) float Ws[128 * 64];   // up to K=128
    __shared__ __align__(16) float As[16 * 68];    // k-major, stride 68

    const int tid  = threadIdx.x;
    const int row0 = blockIdx.x * 64;

    // Stage W entirely (coalesced float4).
    for (int off = tid * 4; off < K * 64; off += 1024) {
        *(float4*)(Ws + off) = *(const float4*)(W + off);
    }

    const int tx = tid & 15;   // col group: cols tx*4 .. tx*4+3
    const int ty = tid >> 4;   // row group: rows ty*4 .. ty*4+3
    const int lr = tid >> 2;   // staging row 0..63
    const int kq = tid & 3;    // staging k-quad 0..3

    float acc[4][4];
#pragma unroll
    for (int i = 0; i < 4; i++)
#pragma unroll
        for (int j = 0; j < 4; j++) acc[i][j] = 0.f;

    const int grow = row0 + lr;
    const float* Arow = A + (size_t)grow * K;

    for (int k0 = 0; k0 < K; k0 += 16) {
        __syncthreads();  // protect prior iteration's As reads
        float4 av = make_float4(0.f, 0.f, 0.f, 0.f);
        if (grow < N) av = *(const float4*)(Arow + k0 + kq * 4);
        if (RELU) {
            av.x = fmaxf(av.x, 0.f); av.y = fmaxf(av.y, 0.f);
            av.z = fmaxf(av.z, 0.f); av.w = fmaxf(av.w, 0.f);
        }
        As[(kq * 4 + 0) * 68 + lr] = av.x;
        As[(kq * 4 + 1) * 68 + lr] = av.y;
        As[(kq * 4 + 2) * 68 + lr] = av.z;
        As[(kq * 4 + 3) * 68 + lr] = av.w;
        __syncthreads();

#pragma unroll
        for (int kk = 0; kk < 16; kk++) {
            float4 a4 = *(const float4*)(As + kk * 68 + ty * 4);
            float4 b4 = *(const float4*)(Ws + (k0 + kk) * 64 + tx * 4);
            float avv[4] = {a4.x, a4.y, a4.z, a4.w};
            float bvv[4] = {b4.x, b4.y, b4.z, b4.w};
#pragma unroll
            for (int i = 0; i < 4; i++)
#pragma unroll
                for (int j = 0; j < 4; j++)
                    acc[i][j] = fmaf(avv[i], bvv[j], acc[i][j]);
        }
    }

#pragma unroll
    for (int i = 0; i < 4; i++) {
        int r = row0 + ty * 4 + i;
        if (r < N) {
            float4 o = make_float4(acc[i][0], acc[i][1], acc[i][2], acc[i][3]);
            *(float4*)(C + (size_t)r * HDIM + tx * 4) = o;
        }
    }
}

// out[rows[e]] += vals[e] * hw[cols[e]]  (64 floats per edge; 16 threads/edge,
// float4 gather + 4 scalar f32 atomics each).
__global__ __launch_bounds__(256) void scatter_add(const float* __restrict__ hw,
                                                   const int* __restrict__ rows,
                                                   const int* __restrict__ cols,
                                                   const float* __restrict__ vals,
                                                   float* __restrict__ out,
                                                   int E) {
    int t = blockIdx.x * 256 + threadIdx.x;
    int e = t >> 4;
    if (e >= E) return;
    int l4 = (t & 15) << 2;
    int c = cols[e];
    int r = rows[e];
    float v = vals[e];
    float4 h4 = *(const float4*)(hw + (size_t)c * HDIM + l4);
    float* o = out + (size_t)r * HDIM + l4;
    atomicAdd(o + 0, v * h4.x);
    atomicAdd(o + 1, v * h4.y);
    atomicAdd(o + 2, v * h4.z);
    atomicAdd(o + 3, v * h4.w);
}

// f_g = concat(relu(h1_g)*att0, relu(e1_g)*att1, (p_g + relu(h1_g))*att2)
// out layout [2, N, 192].
__global__ __launch_bounds__(256) void assemble(const float* __restrict__ h10,
                                                const float* __restrict__ h11,
                                                const float* __restrict__ e10,
                                                const float* __restrict__ e11,
                                                const float* __restrict__ p0,
                                                const float* __restrict__ p1,
                                                const float* __restrict__ att,
                                                float* __restrict__ out,
                                                int N) {
    int t = blockIdx.x * 256 + threadIdx.x;
    if (t >= N * HDIM) return;
    int n = t >> 6;
    int l = t & 63;
    float a0 = att[0], a1 = att[1], a2 = att[2];
    size_t base = (size_t)n * 192 + l;

    float h = fmaxf(h10[t], 0.f);
    float e = fmaxf(e10[t], 0.f);
    float m = p0[t] + h;
    out[base]       = h * a0;
    out[base + 64]  = e * a1;
    out[base + 128] = m * a2;

    h = fmaxf(h11[t], 0.f);
    e = fmaxf(e11[t], 0.f);
    m = p1[t] + h;
    size_t base1 = (size_t)N * 192 + base;
    out[base1]       = h * a0;
    out[base1 + 64]  = e * a1;
    out[base1 + 128] = m * a2;
}

extern "C" void kernel_launch(void* const* d_in, const int* in_sizes, int n_in,
                              void* d_out, int out_size, void* d_ws, size_t ws_size,
                              hipStream_t stream) {
    const float* feat0 = (const float*)d_in[0];
    const float* feat1 = (const float*)d_in[1];
    const int*   rows  = (const int*)d_in[2];
    const int*   cols  = (const int*)d_in[3];
    const float* vals  = (const float*)d_in[4];
    const float* W1    = (const float*)d_in[5];
    const float* W2    = (const float*)d_in[6];
    const float* W3    = (const float*)d_in[7];
    const float* W4    = (const float*)d_in[8];
    const float* W5    = (const float*)d_in[9];
    const float* att   = (const float*)d_in[10];

    const int N = in_sizes[0] / 128;   // 100000
    const int E = in_sizes[2] / 4;     // 1000000
    const size_t NH = (size_t)N * HDIM;

    float* ws  = (float*)d_ws;
    float* h10 = ws + 0 * NH;
    float* h11 = ws + 1 * NH;
    float* e10 = ws + 2 * NH;
    float* e11 = ws + 3 * NH;
    float* A0  = ws + 4 * NH;   // e2, later p
    float* A1  = ws + 5 * NH;
    float* B0  = ws + 6 * NH;   // e3
    float* B1  = ws + 7 * NH;
    float* hw  = ws + 8 * NH;   // per-edge-type GEMM result staging

    const int gblk = (N + 63) / 64;
    const int sblk = (int)(((size_t)E * 16 + 255) / 256);

    static const int ei[4] = {0, 0, 1, 1};
    static const int ej[4] = {0, 1, 0, 1};

    auto layer = [&](const float* in0, const float* in1, const float* W, int K,
                     bool relu_in, float* o0, float* o1) {
        hipMemsetAsync(o0, 0, NH * sizeof(float), stream);
        hipMemsetAsync(o1, 0, NH * sizeof(float), stream);
        const float* ins[2] = {in0, in1};
        float* outs[2] = {o0, o1};
        for (int t = 0; t < 4; t++) {
            const float* Aj = ins[ej[t]];
            const float* Wt = W + (size_t)t * K * HDIM;
            if (relu_in)
                gemm64<1><<<gblk, 256, 0, stream>>>(Aj, Wt, hw, N, K);
            else
                gemm64<0><<<gblk, 256, 0, stream>>>(Aj, Wt, hw, N, K);
            scatter_add<<<sblk, 256, 0, stream>>>(hw, rows + (size_t)t * E,
                                                  cols + (size_t)t * E,
                                                  vals + (size_t)t * E,
                                                  outs[ei[t]], E);
        }
    };

    layer(feat0, feat1, W1, 128, false, h10, h11);  // -> h1 (pre-act)
    layer(h10, h11, W2, 64, true, e10, e11);        // -> e1 (pre-act)
    layer(e10, e11, W3, 64, true, A0, A1);          // -> e2
    layer(A0, A1, W4, 64, true, B0, B1);            // -> e3
    layer(B0, B1, W5, 64, true, A0, A1);            // -> p (no relu on p)

    assemble<<<(int)((NH + 255) / 256), 256, 0, stream>>>(
        h10, h11, e10, e11, A0, A1, att, (float*)d_out, N);
}

// Round 2
// 2414.461 us; speedup vs baseline: 7.2961x; 7.2961x over previous
//
#include <hip/hip_runtime.h>

// ---------------------------------------------------------------------------
// Decagon GCN forward, round 2: atomics -> CSR gather.
// Preprocess once per launch (graph static across 5 layers):
//   histogram -> exclusive scan -> counting-sort edges by destination row.
// Aggregation: one wave per output row, lane = feature; edges of both
// contributing edge types fused into one kernel (no memset, no atomics).
// GEMM: fp32 LDS-tiled VALU (no fp32 MFMA on CDNA4), unchanged from R1.
// ---------------------------------------------------------------------------

#define HDIM 64

// C[N,64] = act(A)[N,K] @ W[K,64], K in {64,128}, act = relu if RELU.
template <int RELU>
__global__ __launch_bounds__(256) void gemm64(const float* __restrict__ A,
                                              const float* __restrict__ W,
                                              float* __restrict__ C,
                                              int N, int K) {
    __shared__ __align__(16) float Ws[128 * 64];
    __shared__ __align__(16) float As[16 * 68];

    const int tid  = threadIdx.x;
    const int row0 = blockIdx.x * 64;

    for (int off = tid * 4; off < K * 64; off += 1024) {
        *(float4*)(Ws + off) = *(const float4*)(W + off);
    }

    const int tx = tid & 15;
    const int ty = tid >> 4;
    const int lr = tid >> 2;
    const int kq = tid & 3;

    float acc[4][4];
#pragma unroll
    for (int i = 0; i < 4; i++)
#pragma unroll
        for (int j = 0; j < 4; j++) acc[i][j] = 0.f;

    const int grow = row0 + lr;
    const float* Arow = A + (size_t)grow * K;

    for (int k0 = 0; k0 < K; k0 += 16) {
        __syncthreads();
        float4 av = make_float4(0.f, 0.f, 0.f, 0.f);
        if (grow < N) av = *(const float4*)(Arow + k0 + kq * 4);
        if (RELU) {
            av.x = fmaxf(av.x, 0.f); av.y = fmaxf(av.y, 0.f);
            av.z = fmaxf(av.z, 0.f); av.w = fmaxf(av.w, 0.f);
        }
        As[(kq * 4 + 0) * 68 + lr] = av.x;
        As[(kq * 4 + 1) * 68 + lr] = av.y;
        As[(kq * 4 + 2) * 68 + lr] = av.z;
        As[(kq * 4 + 3) * 68 + lr] = av.w;
        __syncthreads();

#pragma unroll
        for (int kk = 0; kk < 16; kk++) {
            float4 a4 = *(const float4*)(As + kk * 68 + ty * 4);
            float4 b4 = *(const float4*)(Ws + (k0 + kk) * 64 + tx * 4);
            float avv[4] = {a4.x, a4.y, a4.z, a4.w};
            float bvv[4] = {b4.x, b4.y, b4.z, b4.w};
#pragma unroll
            for (int i = 0; i < 4; i++)
#pragma unroll
                for (int j = 0; j < 4; j++)
                    acc[i][j] = fmaf(avv[i], bvv[j], acc[i][j]);
        }
    }

#pragma unroll
    for (int i = 0; i < 4; i++) {
        int r = row0 + ty * 4 + i;
        if (r < N) {
            float4 o = make_float4(acc[i][0], acc[i][1], acc[i][2], acc[i][3]);
            *(float4*)(C + (size_t)r * HDIM + tx * 4) = o;
        }
    }
}

// --- CSR build ------------------------------------------------------------

__global__ __launch_bounds__(256) void hist1(const int* __restrict__ rows,
                                             int* __restrict__ cnt, int E) {
    int e = blockIdx.x * 256 + threadIdx.x;
    if (e < E) atomicAdd(&cnt[rows[e]], 1);
}

// Per-1024-chunk block sums of cnt[0..M)
__global__ __launch_bounds__(256) void scan_sums(const int* __restrict__ cnt,
                                                 int* __restrict__ partials, int M) {
    __shared__ int red[256];
    int base = blockIdx.x * 1024 + threadIdx.x * 4;
    int s = 0;
#pragma unroll
    for (int j = 0; j < 4; j++) { int i = base + j; if (i < M) s += cnt[i]; }
    red[threadIdx.x] = s;
    __syncthreads();
    for (int off = 128; off > 0; off >>= 1) {
        if (threadIdx.x < off) red[threadIdx.x] += red[threadIdx.x + off];
        __syncthreads();
    }
    if (threadIdx.x == 0) partials[blockIdx.x] = red[0];
}

// Single-block exclusive scan of partials[0..B), B <= 1024.
__global__ __launch_bounds__(1024) void scan_partials(int* __restrict__ partials, int B) {
    __shared__ int buf[1024];
    int t = threadIdx.x;
    int v = (t < B) ? partials[t] : 0;
    buf[t] = v;
    __syncthreads();
    for (int off = 1; off < 1024; off <<= 1) {
        int add = (t >= off) ? buf[t - off] : 0;
        __syncthreads();
        buf[t] += add;
        __syncthreads();
    }
    if (t < B) partials[t] = buf[t] - v;  // exclusive
}

// Final: write exclusive scan to start[] and cursor[] (cnt becomes cursor).
__global__ __launch_bounds__(256) void scan_final(int* __restrict__ cnt,
                                                  const int* __restrict__ partials,
                                                  int* __restrict__ start,
                                                  int M, int total) {
    __shared__ int red[256];
    int tid = threadIdx.x;
    int base = blockIdx.x * 1024 + tid * 4;
    int v[4];
    int s = 0;
#pragma unroll
    for (int j = 0; j < 4; j++) { int i = base + j; v[j] = (i < M) ? cnt[i] : 0; s += v[j]; }
    red[tid] = s;
    __syncthreads();
    int mine = s;
    for (int off = 1; off < 256; off <<= 1) {
        int add = (tid >= off) ? red[tid - off] : 0;
        __syncthreads();
        red[tid] += add;
        __syncthreads();
    }
    int excl = red[tid] - mine + partials[blockIdx.x];
#pragma unroll
    for (int j = 0; j < 4; j++) {
        int i = base + j;
        if (i < M) { start[i] = excl; cnt[i] = excl; excl += v[j]; }
    }
    if (blockIdx.x == 0 && tid == 0) start[M] = total;
}

// Counting-sort one edge type's (col,val) by row into absolute positions.
__global__ __launch_bounds__(256) void reorder(const int* __restrict__ rows,
                                               const int* __restrict__ cols,
                                               const float* __restrict__ vals,
                                               int* __restrict__ cursor,
                                               int* __restrict__ scol,
                                               float* __restrict__ sval, int E) {
    int e = blockIdx.x * 256 + threadIdx.x;
    if (e >= E) return;
    int pos = atomicAdd(&cursor[rows[e]], 1);
    scol[pos] = cols[e];
    sval[pos] = vals[e];
}

// --- fused 2-type CSR gather ---------------------------------------------
// out[i][lane] = sum over edges of type A and B ending at row i of
//                val_e * hw{A,B}[col_e][lane].  One wave per row.
__global__ __launch_bounds__(256) void gather2(const float* __restrict__ hwA,
                                               const float* __restrict__ hwB,
                                               const int* __restrict__ startA,
                                               const int* __restrict__ startB,
                                               const int* __restrict__ scol,
                                               const float* __restrict__ sval,
                                               float* __restrict__ out, int N) {
    int row  = blockIdx.x * 4 + (threadIdx.x >> 6);
    int lane = threadIdx.x & 63;
    if (row >= N) return;
    float acc = 0.f;

    {
        int beg = startA[row], end = startA[row + 1];
        for (int s = beg; s < end; s += 64) {
            int m = end - s; if (m > 64) m = 64;
            int c = 0; float v = 0.f;
            if (lane < m) { c = scol[s + lane]; v = sval[s + lane]; }
            for (int j = 0; j < m; j++) {
                int   cj = __shfl(c, j);
                float vj = __shfl(v, j);
                acc = fmaf(vj, hwA[(size_t)cj * HDIM + lane], acc);
            }
        }
    }
    {
        int beg = startB[row], end = startB[row + 1];
        for (int s = beg; s < end; s += 64) {
            int m = end - s; if (m > 64) m = 64;
            int c = 0; float v = 0.f;
            if (lane < m) { c = scol[s + lane]; v = sval[s + lane]; }
            for (int j = 0; j < m; j++) {
                int   cj = __shfl(c, j);
                float vj = __shfl(v, j);
                acc = fmaf(vj, hwB[(size_t)cj * HDIM + lane], acc);
            }
        }
    }
    out[(size_t)row * HDIM + lane] = acc;
}

// --- epilogue -------------------------------------------------------------

__global__ __launch_bounds__(256) void assemble(const float* __restrict__ h10,
                                                const float* __restrict__ h11,
                                                const float* __restrict__ e10,
                                                const float* __restrict__ e11,
                                                const float* __restrict__ p0,
                                                const float* __restrict__ p1,
                                                const float* __restrict__ att,
                                                float* __restrict__ out,
                                                int N) {
    int t = blockIdx.x * 256 + threadIdx.x;
    if (t >= N * HDIM) return;
    int n = t >> 6;
    int l = t & 63;
    float a0 = att[0], a1 = att[1], a2 = att[2];
    size_t base = (size_t)n * 192 + l;

    float h = fmaxf(h10[t], 0.f);
    float e = fmaxf(e10[t], 0.f);
    float m = p0[t] + h;
    out[base]       = h * a0;
    out[base + 64]  = e * a1;
    out[base + 128] = m * a2;

    h = fmaxf(h11[t], 0.f);
    e = fmaxf(e11[t], 0.f);
    m = p1[t] + h;
    size_t base1 = (size_t)N * 192 + base;
    out[base1]       = h * a0;
    out[base1 + 64]  = e * a1;
    out[base1 + 128] = m * a2;
}

extern "C" void kernel_launch(void* const* d_in, const int* in_sizes, int n_in,
                              void* d_out, int out_size, void* d_ws, size_t ws_size,
                              hipStream_t stream) {
    const float* feat0 = (const float*)d_in[0];
    const float* feat1 = (const float*)d_in[1];
    const int*   rows  = (const int*)d_in[2];
    const int*   cols  = (const int*)d_in[3];
    const float* vals  = (const float*)d_in[4];
    const float* W1    = (const float*)d_in[5];
    const float* W2    = (const float*)d_in[6];
    const float* W3    = (const float*)d_in[7];
    const float* W4    = (const float*)d_in[8];
    const float* W5    = (const float*)d_in[9];
    const float* att   = (const float*)d_in[10];

    const int N = in_sizes[0] / 128;   // 100000
    const int E = in_sizes[2] / 4;     // 1000000
    const size_t NH = (size_t)N * HDIM;
    const int M = 4 * N;               // flat CSR bins across 4 edge types

    float* ws  = (float*)d_ws;
    float* h10 = ws + 0 * NH;
    float* h11 = ws + 1 * NH;
    float* e10 = ws + 2 * NH;
    float* e11 = ws + 3 * NH;
    float* A0  = ws + 4 * NH;   // e2, later p
    float* A1  = ws + 5 * NH;
    float* B0  = ws + 6 * NH;   // e3
    float* B1  = ws + 7 * NH;
    float* hwa = ws + 8 * NH;
    float* hwb = ws + 9 * NH;

    int*   start    = (int*)(ws + 10 * NH);       // M+1
    int*   cursor   = start + (M + 1);            // M (histogram -> cursor)
    int*   scol     = cursor + M;                 // 4E
    float* sval     = (float*)(scol + 4 * E);     // 4E
    int*   partials = (int*)(sval + 4 * E);       // <=1024

    const int gblk = (N + 63) / 64;
    const int eblk = (E + 255) / 256;
    const int B    = (M + 1023) / 1024;

    // ---- CSR build (once; graph reused by all 5 layers) ----
    hipMemsetAsync(cursor, 0, (size_t)M * sizeof(int), stream);
    for (int t = 0; t < 4; t++)
        hist1<<<eblk, 256, 0, stream>>>(rows + (size_t)t * E, cursor + t * N, E);
    scan_sums<<<B, 256, 0, stream>>>(cursor, partials, M);
    scan_partials<<<1, 1024, 0, stream>>>(partials, B);
    scan_final<<<B, 256, 0, stream>>>(cursor, partials, start, M, 4 * E);
    for (int t = 0; t < 4; t++)
        reorder<<<eblk, 256, 0, stream>>>(rows + (size_t)t * E, cols + (size_t)t * E,
                                          vals + (size_t)t * E, cursor + t * N,
                                          scol, sval, E);

    const int gr2 = (N + 3) / 4;

    auto layer = [&](const float* in0, const float* in1, const float* W, int K,
                     bool relu_in, float* o0, float* o1) {
        const float* ins[2] = {in0, in1};
        float* outs[2] = {o0, o1};
        for (int half = 0; half < 2; half++) {
            int tA = half * 2, tB = half * 2 + 1;
            const float* WA = W + (size_t)tA * K * HDIM;
            const float* WB = W + (size_t)tB * K * HDIM;
            if (relu_in) {
                gemm64<1><<<gblk, 256, 0, stream>>>(ins[0], WA, hwa, N, K);
                gemm64<1><<<gblk, 256, 0, stream>>>(ins[1], WB, hwb, N, K);
            } else {
                gemm64<0><<<gblk, 256, 0, stream>>>(ins[0], WA, hwa, N, K);
                gemm64<0><<<gblk, 256, 0, stream>>>(ins[1], WB, hwb, N, K);
            }
            gather2<<<gr2, 256, 0, stream>>>(hwa, hwb, start + tA * N, start + tB * N,
                                             scol, sval, outs[half], N);
        }
    };

    layer(feat0, feat1, W1, 128, false, h10, h11);  // -> h1 (pre-act)
    layer(h10, h11, W2, 64, true, e10, e11);        // -> e1 (pre-act)
    layer(e10, e11, W3, 64, true, A0, A1);          // -> e2
    layer(A0, A1, W4, 64, true, B0, B1);            // -> e3
    layer(B0, B1, W5, 64, true, A0, A1);            // -> p (no relu)

    assemble<<<(int)((NH + 255) / 256), 256, 0, stream>>>(
        h10, h11, e10, e11, A0, A1, att, (float*)d_out, N);
}

// Round 3
// 1811.038 us; speedup vs baseline: 9.7271x; 1.3332x over previous
//
#include <hip/hip_runtime.h>

// ---------------------------------------------------------------------------
// Decagon GCN forward, round 3.
// R2 -> R3: gather2 inner edge loop was latency-serialized (1 load in flight
// per wave). Now unrolled x8 with padded chunks => 8 independent global loads
// per waitcnt (MLP=8), dual accumulators. GEMMs per half batched via gridDim.y.
// ---------------------------------------------------------------------------

#define HDIM 64

// C[N,64] = act(A)[N,K] @ W[K,64].  gridDim.y selects (A,W,C) pair.
template <int RELU>
__global__ __launch_bounds__(256) void gemm64(const float* __restrict__ A0,
                                              const float* __restrict__ W0,
                                              float* __restrict__ C0,
                                              const float* __restrict__ A1,
                                              const float* __restrict__ W1,
                                              float* __restrict__ C1,
                                              int N, int K) {
    __shared__ __align__(16) float Ws[128 * 64];
    __shared__ __align__(16) float As[16 * 68];

    const float* A = blockIdx.y ? A1 : A0;
    const float* W = blockIdx.y ? W1 : W0;
    float*       C = blockIdx.y ? C1 : C0;

    const int tid  = threadIdx.x;
    const int row0 = blockIdx.x * 64;

    for (int off = tid * 4; off < K * 64; off += 1024) {
        *(float4*)(Ws + off) = *(const float4*)(W + off);
    }

    const int tx = tid & 15;
    const int ty = tid >> 4;
    const int lr = tid >> 2;
    const int kq = tid & 3;

    float acc[4][4];
#pragma unroll
    for (int i = 0; i < 4; i++)
#pragma unroll
        for (int j = 0; j < 4; j++) acc[i][j] = 0.f;

    const int grow = row0 + lr;
    const float* Arow = A + (size_t)grow * K;

    for (int k0 = 0; k0 < K; k0 += 16) {
        __syncthreads();
        float4 av = make_float4(0.f, 0.f, 0.f, 0.f);
        if (grow < N) av = *(const float4*)(Arow + k0 + kq * 4);
        if (RELU) {
            av.x = fmaxf(av.x, 0.f); av.y = fmaxf(av.y, 0.f);
            av.z = fmaxf(av.z, 0.f); av.w = fmaxf(av.w, 0.f);
        }
        As[(kq * 4 + 0) * 68 + lr] = av.x;
        As[(kq * 4 + 1) * 68 + lr] = av.y;
        As[(kq * 4 + 2) * 68 + lr] = av.z;
        As[(kq * 4 + 3) * 68 + lr] = av.w;
        __syncthreads();

#pragma unroll
        for (int kk = 0; kk < 16; kk++) {
            float4 a4 = *(const float4*)(As + kk * 68 + ty * 4);
            float4 b4 = *(const float4*)(Ws + (k0 + kk) * 64 + tx * 4);
            float avv[4] = {a4.x, a4.y, a4.z, a4.w};
            float bvv[4] = {b4.x, b4.y, b4.z, b4.w};
#pragma unroll
            for (int i = 0; i < 4; i++)
#pragma unroll
                for (int j = 0; j < 4; j++)
                    acc[i][j] = fmaf(avv[i], bvv[j], acc[i][j]);
        }
    }

#pragma unroll
    for (int i = 0; i < 4; i++) {
        int r = row0 + ty * 4 + i;
        if (r < N) {
            float4 o = make_float4(acc[i][0], acc[i][1], acc[i][2], acc[i][3]);
            *(float4*)(C + (size_t)r * HDIM + tx * 4) = o;
        }
    }
}

// --- CSR build ------------------------------------------------------------

__global__ __launch_bounds__(256) void hist1(const int* __restrict__ rows,
                                             int* __restrict__ cnt, int E) {
    int e = blockIdx.x * 256 + threadIdx.x;
    if (e < E) atomicAdd(&cnt[rows[e]], 1);
}

__global__ __launch_bounds__(256) void scan_sums(const int* __restrict__ cnt,
                                                 int* __restrict__ partials, int M) {
    __shared__ int red[256];
    int base = blockIdx.x * 1024 + threadIdx.x * 4;
    int s = 0;
#pragma unroll
    for (int j = 0; j < 4; j++) { int i = base + j; if (i < M) s += cnt[i]; }
    red[threadIdx.x] = s;
    __syncthreads();
    for (int off = 128; off > 0; off >>= 1) {
        if (threadIdx.x < off) red[threadIdx.x] += red[threadIdx.x + off];
        __syncthreads();
    }
    if (threadIdx.x == 0) partials[blockIdx.x] = red[0];
}

__global__ __launch_bounds__(1024) void scan_partials(int* __restrict__ partials, int B) {
    __shared__ int buf[1024];
    int t = threadIdx.x;
    int v = (t < B) ? partials[t] : 0;
    buf[t] = v;
    __syncthreads();
    for (int off = 1; off < 1024; off <<= 1) {
        int add = (t >= off) ? buf[t - off] : 0;
        __syncthreads();
        buf[t] += add;
        __syncthreads();
    }
    if (t < B) partials[t] = buf[t] - v;  // exclusive
}

__global__ __launch_bounds__(256) void scan_final(int* __restrict__ cnt,
                                                  const int* __restrict__ partials,
                                                  int* __restrict__ start,
                                                  int M, int total) {
    __shared__ int red[256];
    int tid = threadIdx.x;
    int base = blockIdx.x * 1024 + tid * 4;
    int v[4];
    int s = 0;
#pragma unroll
    for (int j = 0; j < 4; j++) { int i = base + j; v[j] = (i < M) ? cnt[i] : 0; s += v[j]; }
    red[tid] = s;
    __syncthreads();
    int mine = s;
    for (int off = 1; off < 256; off <<= 1) {
        int add = (tid >= off) ? red[tid - off] : 0;
        __syncthreads();
        red[tid] += add;
        __syncthreads();
    }
    int excl = red[tid] - mine + partials[blockIdx.x];
#pragma unroll
    for (int j = 0; j < 4; j++) {
        int i = base + j;
        if (i < M) { start[i] = excl; cnt[i] = excl; excl += v[j]; }
    }
    if (blockIdx.x == 0 && tid == 0) start[M] = total;
}

__global__ __launch_bounds__(256) void reorder(const int* __restrict__ rows,
                                               const int* __restrict__ cols,
                                               const float* __restrict__ vals,
                                               int* __restrict__ cursor,
                                               int* __restrict__ scol,
                                               float* __restrict__ sval, int E) {
    int e = blockIdx.x * 256 + threadIdx.x;
    if (e >= E) return;
    int pos = atomicAdd(&cursor[rows[e]], 1);
    scol[pos] = cols[e];
    sval[pos] = vals[e];
}

// --- fused 2-type CSR gather, MLP=8 ---------------------------------------
// out[i][lane] = sum_{e in rowA(i)} val_e*hwA[col_e][lane]
//              + sum_{e in rowB(i)} val_e*hwB[col_e][lane].   One wave/row.
__global__ __launch_bounds__(256) void gather2(const float* __restrict__ hwA,
                                               const float* __restrict__ hwB,
                                               const int* __restrict__ startA,
                                               const int* __restrict__ startB,
                                               const int* __restrict__ scol,
                                               const float* __restrict__ sval,
                                               float* __restrict__ out, int N) {
    int row  = blockIdx.x * 4 + (threadIdx.x >> 6);
    int lane = threadIdx.x & 63;
    if (row >= N) return;
    float acc0 = 0.f, acc1 = 0.f;

    const float* hws[2] = {hwA, hwB};
    const int*   sts[2] = {startA, startB};

#pragma unroll
    for (int p = 0; p < 2; p++) {
        const float* hw = hws[p];
        int beg = sts[p][row], end = sts[p][row + 1];
        for (int s = beg; s < end; s += 64) {
            int m = end - s; if (m > 64) m = 64;
            int c = 0; float v = 0.f;
            if (lane < m) { c = scol[s + lane]; v = sval[s + lane]; }
            int mp = (m + 7) & ~7;   // pad: lanes >= m carry c=0,v=0 (safe)
            for (int j = 0; j < mp; j += 8) {
                float h[8], vv[8];
#pragma unroll
                for (int u = 0; u < 8; u++) {
                    int   cj = __shfl(c, j + u);
                    vv[u]    = __shfl(v, j + u);
                    h[u]     = hw[(size_t)cj * HDIM + lane];
                }
#pragma unroll
                for (int u = 0; u < 8; u += 2) {
                    acc0 = fmaf(vv[u],     h[u],     acc0);
                    acc1 = fmaf(vv[u + 1], h[u + 1], acc1);
                }
            }
        }
    }
    out[(size_t)row * HDIM + lane] = acc0 + acc1;
}

// --- epilogue -------------------------------------------------------------

__global__ __launch_bounds__(256) void assemble(const float* __restrict__ h10,
                                                const float* __restrict__ h11,
                                                const float* __restrict__ e10,
                                                const float* __restrict__ e11,
                                                const float* __restrict__ p0,
                                                const float* __restrict__ p1,
                                                const float* __restrict__ att,
                                                float* __restrict__ out,
                                                int N) {
    int t = blockIdx.x * 256 + threadIdx.x;
    if (t >= N * HDIM) return;
    int n = t >> 6;
    int l = t & 63;
    float a0 = att[0], a1 = att[1], a2 = att[2];
    size_t base = (size_t)n * 192 + l;

    float h = fmaxf(h10[t], 0.f);
    float e = fmaxf(e10[t], 0.f);
    float m = p0[t] + h;
    out[base]       = h * a0;
    out[base + 64]  = e * a1;
    out[base + 128] = m * a2;

    h = fmaxf(h11[t], 0.f);
    e = fmaxf(e11[t], 0.f);
    m = p1[t] + h;
    size_t base1 = (size_t)N * 192 + base;
    out[base1]       = h * a0;
    out[base1 + 64]  = e * a1;
    out[base1 + 128] = m * a2;
}

extern "C" void kernel_launch(void* const* d_in, const int* in_sizes, int n_in,
                              void* d_out, int out_size, void* d_ws, size_t ws_size,
                              hipStream_t stream) {
    const float* feat0 = (const float*)d_in[0];
    const float* feat1 = (const float*)d_in[1];
    const int*   rows  = (const int*)d_in[2];
    const int*   cols  = (const int*)d_in[3];
    const float* vals  = (const float*)d_in[4];
    const float* W1    = (const float*)d_in[5];
    const float* W2    = (const float*)d_in[6];
    const float* W3    = (const float*)d_in[7];
    const float* W4    = (const float*)d_in[8];
    const float* W5    = (const float*)d_in[9];
    const float* att   = (const float*)d_in[10];

    const int N = in_sizes[0] / 128;   // 100000
    const int E = in_sizes[2] / 4;     // 1000000
    const size_t NH = (size_t)N * HDIM;
    const int M = 4 * N;

    float* ws  = (float*)d_ws;
    float* h10 = ws + 0 * NH;
    float* h11 = ws + 1 * NH;
    float* e10 = ws + 2 * NH;
    float* e11 = ws + 3 * NH;
    float* A0  = ws + 4 * NH;   // e2, later p
    float* A1  = ws + 5 * NH;
    float* B0  = ws + 6 * NH;   // e3
    float* B1  = ws + 7 * NH;
    float* hwa = ws + 8 * NH;
    float* hwb = ws + 9 * NH;

    int*   start    = (int*)(ws + 10 * NH);       // M+1
    int*   cursor   = start + (M + 1);            // M
    int*   scol     = cursor + M;                 // 4E
    float* sval     = (float*)(scol + 4 * E);     // 4E
    int*   partials = (int*)(sval + 4 * E);       // <=1024

    const int gblk = (N + 63) / 64;
    const int eblk = (E + 255) / 256;
    const int B    = (M + 1023) / 1024;

    // ---- CSR build (once; graph reused by all 5 layers) ----
    hipMemsetAsync(cursor, 0, (size_t)M * sizeof(int), stream);
    for (int t = 0; t < 4; t++)
        hist1<<<eblk, 256, 0, stream>>>(rows + (size_t)t * E, cursor + t * N, E);
    scan_sums<<<B, 256, 0, stream>>>(cursor, partials, M);
    scan_partials<<<1, 1024, 0, stream>>>(partials, B);
    scan_final<<<B, 256, 0, stream>>>(cursor, partials, start, M, 4 * E);
    for (int t = 0; t < 4; t++)
        reorder<<<eblk, 256, 0, stream>>>(rows + (size_t)t * E, cols + (size_t)t * E,
                                          vals + (size_t)t * E, cursor + t * N,
                                          scol, sval, E);

    const int gr2 = (N + 3) / 4;

    auto layer = [&](const float* in0, const float* in1, const float* W, int K,
                     bool relu_in, float* o0, float* o1) {
        for (int half = 0; half < 2; half++) {
            int tA = half * 2, tB = half * 2 + 1;
            const float* WA = W + (size_t)tA * K * HDIM;
            const float* WB = W + (size_t)tB * K * HDIM;
            dim3 grid(gblk, 2);
            if (relu_in)
                gemm64<1><<<grid, 256, 0, stream>>>(in0, WA, hwa, in1, WB, hwb, N, K);
            else
                gemm64<0><<<grid, 256, 0, stream>>>(in0, WA, hwa, in1, WB, hwb, N, K);
            gather2<<<gr2, 256, 0, stream>>>(hwa, hwb, start + tA * N, start + tB * N,
                                             scol, sval, half ? o1 : o0, N);
        }
    };

    layer(feat0, feat1, W1, 128, false, h10, h11);  // -> h1 (pre-act)
    layer(h10, h11, W2, 64, true, e10, e11);        // -> e1 (pre-act)
    layer(e10, e11, W3, 64, true, A0, A1);          // -> e2
    layer(A0, A1, W4, 64, true, B0, B1);            // -> e3
    layer(B0, B1, W5, 64, true, A0, A1);            // -> p (no relu)

    assemble<<<(int)((NH + 255) / 256), 256, 0, stream>>>(
        h10, h11, e10, e11, A0, A1, att, (float*)d_out, N);
}